// Round 4
// baseline (235.454 us; speedup 1.0000x reference)
//
#include <hip/hip_runtime.h>
#include <hip/hip_bf16.h>

#define NB 4
#define CC 384
#define HEADS 8
#define HD 48
#define NN 16384          // H*W
#define NROWS (NB*CC)     // 1536

typedef __attribute__((ext_vector_type(8))) short bf16x8;
typedef __attribute__((ext_vector_type(4))) float f32x4;

__device__ __forceinline__ unsigned short f2bf(float f) {
  __hip_bfloat16 h = __float2bfloat16(f);
  return __builtin_bit_cast(unsigned short, h);
}

// ---------------- K1: row rms + normalized bf16 copy of in2 ----------------
__global__ __launch_bounds__(256) void k_norms(
    const float* __restrict__ in1, const float* __restrict__ in2,
    float* __restrict__ rinv_q, float* __restrict__ rinv_k,
    unsigned short* __restrict__ kbf)
{
  int row = blockIdx.x;            // 0..3071
  bool isK = row >= NROWS;
  int r = isK ? row - NROWS : row;
  const float4* src = (const float4*)((isK ? in2 : in1) + (size_t)r * NN);
  float s = 0.f;
  #pragma unroll 4
  for (int i = threadIdx.x; i < NN/4; i += 256) {
    float4 v = src[i];
    s += v.x*v.x + v.y*v.y + v.z*v.z + v.w*v.w;
  }
  #pragma unroll
  for (int off = 32; off; off >>= 1) s += __shfl_down(s, off);
  __shared__ float wsum[4];
  __shared__ float rshare;
  if ((threadIdx.x & 63) == 0) wsum[threadIdx.x >> 6] = s;
  __syncthreads();
  if (threadIdx.x == 0) {
    float t = wsum[0] + wsum[1] + wsum[2] + wsum[3];
    float rinv = 1.f / fmaxf(sqrtf(t), 1e-12f);
    rshare = rinv;
    (isK ? rinv_k : rinv_q)[r] = rinv;
  }
  __syncthreads();
  if (isK) {
    float rinv = rshare;
    ushort4* dst = (ushort4*)(kbf + (size_t)r * NN);
    #pragma unroll 4
    for (int i = threadIdx.x; i < NN/4; i += 256) {
      float4 v = src[i];
      ushort4 o;
      o.x = f2bf(v.x * rinv); o.y = f2bf(v.y * rinv);
      o.z = f2bf(v.z * rinv); o.w = f2bf(v.w * rinv);
      dst[i] = o;
    }
  }
}

// ---------------- K2: Gram (normalized q . normalized k), split-K partials ----
__global__ __launch_bounds__(256) void k_gram(
    const float* __restrict__ in1, const unsigned short* __restrict__ kbf,
    const float* __restrict__ rinv_q, float* __restrict__ partial)
{
  int bh = blockIdx.x;     // 32
  int chunk = blockIdx.y;  // 16
  int wave = threadIdx.x >> 6, lane = threadIdx.x & 63;
  int b = bh >> 3, h = bh & 7;
  size_t base = ((size_t)(b*CC + h*HD)) * NN;
  const float* rq = rinv_q + b*CC + h*HD;
  int lrow = lane & 15, lk = (lane >> 4) << 3;
  int kstart = chunk*1024 + wave*256;
  f32x4 acc[3][3] = {};
  for (int ks = 0; ks < 8; ++ks) {
    int kpos = kstart + ks*32 + lk;
    bf16x8 a[3], bb[3];
    #pragma unroll
    for (int t = 0; t < 3; ++t) {
      int rr = t*16 + lrow;
      const float* p = in1 + base + (size_t)rr * NN + kpos;
      float4 v0 = *(const float4*)p;
      float4 v1 = *((const float4*)p + 1);
      float rv = rq[rr];
      union { bf16x8 v; unsigned short u[8]; } ua;
      ua.u[0]=f2bf(v0.x*rv); ua.u[1]=f2bf(v0.y*rv);
      ua.u[2]=f2bf(v0.z*rv); ua.u[3]=f2bf(v0.w*rv);
      ua.u[4]=f2bf(v1.x*rv); ua.u[5]=f2bf(v1.y*rv);
      ua.u[6]=f2bf(v1.z*rv); ua.u[7]=f2bf(v1.w*rv);
      a[t] = ua.v;
      bb[t] = *(const bf16x8*)(kbf + base + (size_t)rr * NN + kpos);
    }
    #pragma unroll
    for (int i = 0; i < 3; ++i)
      #pragma unroll
      for (int j = 0; j < 3; ++j)
        acc[i][j] = __builtin_amdgcn_mfma_f32_16x16x32_bf16(a[i], bb[j], acc[i][j], 0, 0, 0);
  }
  float* pout = partial + ((size_t)bh*64 + (size_t)chunk*4 + wave) * (HD*HD);
  #pragma unroll
  for (int i = 0; i < 3; ++i)
    #pragma unroll
    for (int j = 0; j < 3; ++j)
      #pragma unroll
      for (int m = 0; m < 4; ++m) {
        int rr = i*16 + (lane>>4)*4 + m;
        int cc2 = j*16 + (lane&15);
        pout[rr*HD + cc2] = acc[i][j][m];
      }
}

// ---------------- K3: reduce + softmax + M = projW_h @ attn_h (bf16) --------
__global__ __launch_bounds__(256) void k_softmax_m(
    const float* __restrict__ partial, const float* __restrict__ temp,
    const float* __restrict__ proj_w, unsigned short* __restrict__ Mbf)
{
  int bh = blockIdx.x; int b = bh >> 3, h = bh & 7;
  __shared__ float attn[HD][HD+1];
  const float* p = partial + (size_t)bh * 64 * (HD*HD);
  float tscale = temp[h];
  for (int e = threadIdx.x; e < HD*HD; e += 256) {
    float s = 0.f;
    #pragma unroll 8
    for (int c2 = 0; c2 < 64; ++c2) s += p[(size_t)c2*(HD*HD) + e];
    attn[e/HD][e%HD] = s * tscale;
  }
  __syncthreads();
  if (threadIdx.x < HD) {
    float* rowp = attn[threadIdx.x];
    float m = rowp[0];
    for (int j = 1; j < HD; ++j) m = fmaxf(m, rowp[j]);
    float sum = 0.f;
    for (int j = 0; j < HD; ++j) { float e = expf(rowp[j]-m); rowp[j] = e; sum += e; }
    float inv = 1.f / sum;
    for (int j = 0; j < HD; ++j) rowp[j] *= inv;
  }
  __syncthreads();
  for (int o = threadIdx.x; o < CC; o += 256) {
    const float* wr = proj_w + (size_t)o*CC + h*HD;
    float wv[HD];
    #pragma unroll
    for (int c2 = 0; c2 < HD; ++c2) wv[c2] = wr[c2];
    unsigned short* mo = Mbf + ((size_t)b*CC + o)*CC + h*HD;
    for (int d = 0; d < HD; ++d) {
      float s = 0.f;
      #pragma unroll
      for (int c2 = 0; c2 < HD; ++c2) s += wv[c2]*attn[c2][d];
      mo[d] = f2bf(s);
    }
  }
}

// ---------------- K5: out = M @ kbf + bias  (384x16384x384 per batch) -------
#define BM 128
#define BN 128
#define BK 64

__global__ __launch_bounds__(256) void k_final(
    const unsigned short* __restrict__ kbf, const unsigned short* __restrict__ Mbf,
    const float* __restrict__ bias, float* __restrict__ out)
{
  int b = blockIdx.z;
  int bm = blockIdx.y * BM, bn = blockIdx.x * BN;
  int tid = threadIdx.x, lane = tid & 63, wave = tid >> 6;
  int wrow = wave >> 1, wcol = wave & 1;
  __shared__ unsigned short Bt[BN * BK];   // transposed+swizzled [n][k], 16 KB
  char* btb = (char*)Bt;
  const unsigned short* kb = kbf + (size_t)b * CC * NN;
  const unsigned short* Mb = Mbf + (size_t)b * CC * CC;
  f32x4 acc[4][4] = {};
  int lrow = lane & 15, lkg = lane >> 4;
  for (int k0 = 0; k0 < CC; k0 += BK) {
    // stage B tile (BK rows x BN cols) transposed into LDS, chunk-XOR swizzled
    #pragma unroll
    for (int s = 0; s < 2; ++s) {
      int slot = tid + s*256;
      int cp = slot >> 4;        // dword column (pair of k/channel rows), 0..31
      int ng = slot & 15;        // group of 8 n-columns
      int n0 = ng * 8;
      int c = k0 + cp*2;
      union { uint4 q; unsigned short u[8]; } r0, r1;
      r0.q = *(const uint4*)(kb + (size_t)c*NN + bn + n0);
      r1.q = *(const uint4*)(kb + (size_t)(c+1)*NN + bn + n0);
      #pragma unroll
      for (int i = 0; i < 8; ++i) {
        int n = n0 + i;
        unsigned int val = (unsigned int)r0.u[i] | ((unsigned int)r1.u[i] << 16);
        int pc = (cp>>2) ^ (n & 7) ^ ((n >> 3) & 7);
        *(unsigned int*)(btb + n*128 + (pc<<4) + ((cp&3)<<2)) = val;
      }
    }
    __syncthreads();
    #pragma unroll
    for (int kk = 0; kk < BK; kk += 32) {
      bf16x8 af[4], bfr[4];
      #pragma unroll
      for (int t = 0; t < 4; ++t) {
        int o = bm + wrow*64 + t*16 + lrow;
        af[t] = *(const bf16x8*)(Mb + (size_t)o*CC + (k0 + kk + (lkg<<3)));
        int n = wcol*64 + t*16 + lrow;
        int lc = (kk>>3) + lkg;
        int pc = lc ^ (n & 7) ^ ((n >> 3) & 7);
        bfr[t] = *(const bf16x8*)(btb + n*128 + (pc<<4));
      }
      #pragma unroll
      for (int i = 0; i < 4; ++i)
        #pragma unroll
        for (int j = 0; j < 4; ++j)
          acc[i][j] = __builtin_amdgcn_mfma_f32_16x16x32_bf16(af[i], bfr[j], acc[i][j], 0, 0, 0);
    }
    __syncthreads();
  }
  #pragma unroll
  for (int i = 0; i < 4; ++i) {
    int obase = bm + wrow*64 + i*16 + lkg*4;
    #pragma unroll
    for (int j = 0; j < 4; ++j) {
      int n = bn + wcol*64 + j*16 + lrow;
      #pragma unroll
      for (int m = 0; m < 4; ++m) {
        int o = obase + m;
        out[((size_t)b*CC + o)*NN + n] = acc[i][j][m] + bias[o];
      }
    }
  }
}

extern "C" void kernel_launch(void* const* d_in, const int* in_sizes, int n_in,
                              void* d_out, int out_size, void* d_ws, size_t ws_size,
                              hipStream_t stream)
{
  const float* in1    = (const float*)d_in[0];
  const float* in2    = (const float*)d_in[1];
  const float* temp   = (const float*)d_in[2];
  const float* proj_w = (const float*)d_in[3];
  const float* proj_b = (const float*)d_in[4];
  float* out = (float*)d_out;
  char* ws = (char*)d_ws;

  float* rinv_q = (float*)ws;                               // 1536 f32
  float* rinv_k = (float*)(ws + 6144);                      // 1536 f32
  unsigned short* kbf = (unsigned short*)(ws + 16384);      // 50331648 B
  float* partial = (float*)(ws + 16384 + 50331648);         // 18874368 B
  unsigned short* Mbf = (unsigned short*)(ws + 16384 + 50331648 + 18874368); // 1179648 B

  k_norms<<<dim3(2*NROWS), dim3(256), 0, stream>>>(in1, in2, rinv_q, rinv_k, kbf);
  k_gram<<<dim3(32, 16), dim3(256), 0, stream>>>(in1, kbf, rinv_q, partial);
  k_softmax_m<<<dim3(32), dim3(256), 0, stream>>>(partial, temp, proj_w, Mbf);
  k_final<<<dim3(NN/BN, CC/BM, NB), dim3(256), 0, stream>>>(kbf, Mbf, proj_b, out);
}

// Round 5
// 171.583 us; speedup vs baseline: 1.3722x; 1.3722x over previous
//
#include <hip/hip_runtime.h>
#include <hip/hip_bf16.h>

#define NB 4
#define CC 384
#define HEADS 8
#define HD 48
#define NN 16384          // H*W
#define NROWS (NB*CC)     // 1536

typedef __attribute__((ext_vector_type(8))) short bf16x8;
typedef __attribute__((ext_vector_type(4))) float f32x4;

__device__ __forceinline__ unsigned short f2bf(float f) {
  __hip_bfloat16 h = __float2bfloat16(f);
  return __builtin_bit_cast(unsigned short, h);
}

// ---------------- K1: row rms + normalized bf16 copy of in2 ----------------
__global__ __launch_bounds__(256) void k_norms(
    const float* __restrict__ in1, const float* __restrict__ in2,
    float* __restrict__ rinv_q, float* __restrict__ rinv_k,
    unsigned short* __restrict__ kbf)
{
  int row = blockIdx.x;            // 0..3071
  bool isK = row >= NROWS;
  int r = isK ? row - NROWS : row;
  const float4* src = (const float4*)((isK ? in2 : in1) + (size_t)r * NN);
  float s = 0.f;
  #pragma unroll 4
  for (int i = threadIdx.x; i < NN/4; i += 256) {
    float4 v = src[i];
    s += v.x*v.x + v.y*v.y + v.z*v.z + v.w*v.w;
  }
  #pragma unroll
  for (int off = 32; off; off >>= 1) s += __shfl_down(s, off);
  __shared__ float wsum[4];
  __shared__ float rshare;
  if ((threadIdx.x & 63) == 0) wsum[threadIdx.x >> 6] = s;
  __syncthreads();
  if (threadIdx.x == 0) {
    float t = wsum[0] + wsum[1] + wsum[2] + wsum[3];
    float rinv = 1.f / fmaxf(sqrtf(t), 1e-12f);
    rshare = rinv;
    (isK ? rinv_k : rinv_q)[r] = rinv;
  }
  __syncthreads();
  if (isK) {
    float rinv = rshare;
    ushort4* dst = (ushort4*)(kbf + (size_t)r * NN);
    #pragma unroll 4
    for (int i = threadIdx.x; i < NN/4; i += 256) {
      float4 v = src[i];
      ushort4 o;
      o.x = f2bf(v.x * rinv); o.y = f2bf(v.y * rinv);
      o.z = f2bf(v.z * rinv); o.w = f2bf(v.w * rinv);
      dst[i] = o;
    }
  }
}

// ---------------- K2: Gram (normalized q . normalized k), split-K partials ----
// Now with intra-block cross-wave reduction: one partial per block (16/bh).
__global__ __launch_bounds__(256) void k_gram(
    const float* __restrict__ in1, const unsigned short* __restrict__ kbf,
    const float* __restrict__ rinv_q, float* __restrict__ partial)
{
  int bh = blockIdx.x;     // 32
  int chunk = blockIdx.y;  // 16
  int wave = threadIdx.x >> 6, lane = threadIdx.x & 63;
  int b = bh >> 3, h = bh & 7;
  size_t base = ((size_t)(b*CC + h*HD)) * NN;
  const float* rq = rinv_q + b*CC + h*HD;
  int lrow = lane & 15, lk = (lane >> 4) << 3;
  int kstart = chunk*1024 + wave*256;
  f32x4 acc[3][3] = {};
  for (int ks = 0; ks < 8; ++ks) {
    int kpos = kstart + ks*32 + lk;
    bf16x8 a[3], bb[3];
    #pragma unroll
    for (int t = 0; t < 3; ++t) {
      int rr = t*16 + lrow;
      const float* p = in1 + base + (size_t)rr * NN + kpos;
      float4 v0 = *(const float4*)p;
      float4 v1 = *((const float4*)p + 1);
      float rv = rq[rr];
      union { bf16x8 v; unsigned short u[8]; } ua;
      ua.u[0]=f2bf(v0.x*rv); ua.u[1]=f2bf(v0.y*rv);
      ua.u[2]=f2bf(v0.z*rv); ua.u[3]=f2bf(v0.w*rv);
      ua.u[4]=f2bf(v1.x*rv); ua.u[5]=f2bf(v1.y*rv);
      ua.u[6]=f2bf(v1.z*rv); ua.u[7]=f2bf(v1.w*rv);
      a[t] = ua.v;
      bb[t] = *(const bf16x8*)(kbf + base + (size_t)rr * NN + kpos);
    }
    #pragma unroll
    for (int i = 0; i < 3; ++i)
      #pragma unroll
      for (int j = 0; j < 3; ++j)
        acc[i][j] = __builtin_amdgcn_mfma_f32_16x16x32_bf16(a[i], bb[j], acc[i][j], 0, 0, 0);
  }
  // cross-wave reduce in LDS: [wave][rr][cc+pad]
  __shared__ float red[4][HD][HD+1];
  #pragma unroll
  for (int i = 0; i < 3; ++i)
    #pragma unroll
    for (int j = 0; j < 3; ++j)
      #pragma unroll
      for (int m = 0; m < 4; ++m) {
        int rr = i*16 + (lane>>4)*4 + m;
        int cc2 = j*16 + (lane&15);
        red[wave][rr][cc2] = acc[i][j][m];
      }
  __syncthreads();
  float* pout = partial + ((size_t)bh*16 + chunk) * (HD*HD);
  for (int e = threadIdx.x; e < HD*HD; e += 256) {
    int r = e / HD, c = e % HD;
    pout[e] = red[0][r][c] + red[1][r][c] + red[2][r][c] + red[3][r][c];
  }
}

// ---------------- K3a: reduce 16 partials + temperature + softmax ----------
__global__ __launch_bounds__(256) void k_redsm(
    const float* __restrict__ partial, const float* __restrict__ temp,
    float* __restrict__ attn_out)
{
  int bh = blockIdx.x; int h = bh & 7;
  __shared__ float attn[HD][HD+1];
  const float* p = partial + (size_t)bh * 16 * (HD*HD);
  float tscale = temp[h];
  for (int e = threadIdx.x; e < HD*HD; e += 256) {
    float s = 0.f;
    #pragma unroll
    for (int c2 = 0; c2 < 16; ++c2) s += p[c2*(HD*HD) + e];
    attn[e/HD][e%HD] = s * tscale;
  }
  __syncthreads();
  if (threadIdx.x < HD) {
    float* rowp = attn[threadIdx.x];
    float m = rowp[0];
    for (int j = 1; j < HD; ++j) m = fmaxf(m, rowp[j]);
    float sum = 0.f;
    for (int j = 0; j < HD; ++j) { float e = expf(rowp[j]-m); rowp[j] = e; sum += e; }
    float inv = 1.f / sum;
    for (int j = 0; j < HD; ++j) rowp[j] *= inv;
  }
  __syncthreads();
  float* ao = attn_out + (size_t)bh * (HD*HD);
  for (int e = threadIdx.x; e < HD*HD; e += 256)
    ao[e] = attn[e/HD][e%HD];
}

// ---------------- K3b: M = projW_h @ attn_h (bf16), LDS-staged ------------
__global__ __launch_bounds__(256) void k_m(
    const float* __restrict__ attn, const float* __restrict__ proj_w,
    unsigned short* __restrict__ Mbf)
{
  int b = blockIdx.x, ot = blockIdx.y;  // grid (4, 24)
  int o0 = ot * 16;
  __shared__ float sw[16*CC];           // 24.6 KB
  __shared__ float sa[HEADS*HD*HD];     // 73.7 KB
  const float* ab = attn + (size_t)b * HEADS * HD * HD;
  for (int i = threadIdx.x; i < HEADS*HD*HD; i += 256) sa[i] = ab[i];
  for (int i = threadIdx.x; i < 16*CC; i += 256)
    sw[i] = proj_w[(size_t)(o0 + i/CC)*CC + (i%CC)];
  __syncthreads();
  for (int idx = threadIdx.x; idx < 16*CC; idx += 256) {
    int o = idx / CC, col = idx % CC;
    int h = col / HD, d = col % HD;
    const float* wp = sw + o*CC + h*HD;
    const float* ap = sa + h*HD*HD + d;
    float s = 0.f;
    #pragma unroll
    for (int c2 = 0; c2 < HD; ++c2) s += wp[c2] * ap[c2*HD];
    Mbf[((size_t)b*CC + o0 + o)*CC + col] = f2bf(s);
  }
}

// ---------------- K5: out = M @ kbf + bias  (384x16384x384 per batch) -------
#define BM 128
#define BN 128
#define BK 64

__global__ __launch_bounds__(256) void k_final(
    const unsigned short* __restrict__ kbf, const unsigned short* __restrict__ Mbf,
    const float* __restrict__ bias, float* __restrict__ out)
{
  int b = blockIdx.z;
  int bm = blockIdx.y * BM, bn = blockIdx.x * BN;
  int tid = threadIdx.x, lane = tid & 63, wave = tid >> 6;
  int wrow = wave >> 1, wcol = wave & 1;
  __shared__ unsigned short Bt[BN * BK];   // transposed+swizzled [n][k], 16 KB
  char* btb = (char*)Bt;
  const unsigned short* kb = kbf + (size_t)b * CC * NN;
  const unsigned short* Mb = Mbf + (size_t)b * CC * CC;
  f32x4 acc[4][4] = {};
  int lrow = lane & 15, lkg = lane >> 4;
  for (int k0 = 0; k0 < CC; k0 += BK) {
    // stage B tile (BK rows x BN cols) transposed into LDS, chunk-XOR swizzled
    #pragma unroll
    for (int s = 0; s < 2; ++s) {
      int slot = tid + s*256;
      int cp = slot >> 4;        // dword column (pair of k/channel rows), 0..31
      int ng = slot & 15;        // group of 8 n-columns
      int n0 = ng * 8;
      int c = k0 + cp*2;
      union { uint4 q; unsigned short u[8]; } r0, r1;
      r0.q = *(const uint4*)(kb + (size_t)c*NN + bn + n0);
      r1.q = *(const uint4*)(kb + (size_t)(c+1)*NN + bn + n0);
      #pragma unroll
      for (int i = 0; i < 8; ++i) {
        int n = n0 + i;
        unsigned int val = (unsigned int)r0.u[i] | ((unsigned int)r1.u[i] << 16);
        int pc = (cp>>2) ^ (n & 7) ^ ((n >> 3) & 7);
        *(unsigned int*)(btb + n*128 + (pc<<4) + ((cp&3)<<2)) = val;
      }
    }
    __syncthreads();
    #pragma unroll
    for (int kk = 0; kk < BK; kk += 32) {
      bf16x8 af[4], bfr[4];
      #pragma unroll
      for (int t = 0; t < 4; ++t) {
        int o = bm + wrow*64 + t*16 + lrow;
        af[t] = *(const bf16x8*)(Mb + (size_t)o*CC + (k0 + kk + (lkg<<3)));
        int n = wcol*64 + t*16 + lrow;
        int lc = (kk>>3) + lkg;
        int pc = lc ^ (n & 7) ^ ((n >> 3) & 7);
        bfr[t] = *(const bf16x8*)(btb + n*128 + (pc<<4));
      }
      #pragma unroll
      for (int i = 0; i < 4; ++i)
        #pragma unroll
        for (int j = 0; j < 4; ++j)
          acc[i][j] = __builtin_amdgcn_mfma_f32_16x16x32_bf16(af[i], bfr[j], acc[i][j], 0, 0, 0);
    }
    __syncthreads();
  }
  #pragma unroll
  for (int i = 0; i < 4; ++i) {
    int obase = bm + wrow*64 + i*16 + lkg*4;
    #pragma unroll
    for (int j = 0; j < 4; ++j) {
      int n = bn + wcol*64 + j*16 + lrow;
      #pragma unroll
      for (int m = 0; m < 4; ++m) {
        int o = obase + m;
        out[((size_t)b*CC + o)*NN + n] = acc[i][j][m] + bias[o];
      }
    }
  }
}

extern "C" void kernel_launch(void* const* d_in, const int* in_sizes, int n_in,
                              void* d_out, int out_size, void* d_ws, size_t ws_size,
                              hipStream_t stream)
{
  const float* in1    = (const float*)d_in[0];
  const float* in2    = (const float*)d_in[1];
  const float* temp   = (const float*)d_in[2];
  const float* proj_w = (const float*)d_in[3];
  const float* proj_b = (const float*)d_in[4];
  float* out = (float*)d_out;
  char* ws = (char*)d_ws;

  float* rinv_q = (float*)ws;                               // 6144 B
  float* rinv_k = (float*)(ws + 6144);                      // 6144 B
  unsigned short* kbf = (unsigned short*)(ws + 16384);      // 50331648 B
  float* partial = (float*)(ws + 16384 + 50331648);         // 32*16*2304*4 = 4718592 B
  float* attn_out = (float*)(ws + 16384 + 50331648 + 4718592);   // 294912 B
  unsigned short* Mbf = (unsigned short*)(ws + 16384 + 50331648 + 4718592 + 294912); // 1179648 B

  k_norms<<<dim3(2*NROWS), dim3(256), 0, stream>>>(in1, in2, rinv_q, rinv_k, kbf);
  k_gram<<<dim3(32, 16), dim3(256), 0, stream>>>(in1, kbf, rinv_q, partial);
  k_redsm<<<dim3(32), dim3(256), 0, stream>>>(partial, temp, attn_out);
  k_m<<<dim3(NB, 24), dim3(256), 0, stream>>>(attn_out, proj_w, Mbf);
  k_final<<<dim3(NN/BN, CC/BM, NB), dim3(256), 0, stream>>>(kbf, Mbf, proj_b, out);
}

// Round 7
// 158.579 us; speedup vs baseline: 1.4848x; 1.0820x over previous
//
#include <hip/hip_runtime.h>
#include <hip/hip_bf16.h>

#define NB 4
#define CC 384
#define HEADS 8
#define HD 48
#define NN 16384          // H*W
#define NROWS (NB*CC)     // 1536

typedef __attribute__((ext_vector_type(8))) short bf16x8;
typedef __attribute__((ext_vector_type(4))) float f32x4;

__device__ __forceinline__ unsigned short f2bf(float f) {
  __hip_bfloat16 h = __float2bfloat16(f);
  return __builtin_bit_cast(unsigned short, h);
}

// ---------------- K1: row rms -> normalized bf16 copies of in1 AND in2 ------
// Register-resident: one global read pass, convert from regs, no re-read.
__global__ __launch_bounds__(256) void k_norms(
    const float* __restrict__ in1, const float* __restrict__ in2,
    unsigned short* __restrict__ qbf, unsigned short* __restrict__ kbf)
{
  int row = blockIdx.x;            // 0..3071
  bool isK = row >= NROWS;
  int r = isK ? row - NROWS : row;
  const float4* src = (const float4*)((isK ? in2 : in1) + (size_t)r * NN);
  float4 v[16];
  #pragma unroll
  for (int i = 0; i < 16; ++i) v[i] = src[threadIdx.x + i*256];
  float s0 = 0.f, s1 = 0.f, s2 = 0.f, s3 = 0.f;
  #pragma unroll
  for (int i = 0; i < 16; i += 4) {
    s0 += v[i+0].x*v[i+0].x + v[i+0].y*v[i+0].y + v[i+0].z*v[i+0].z + v[i+0].w*v[i+0].w;
    s1 += v[i+1].x*v[i+1].x + v[i+1].y*v[i+1].y + v[i+1].z*v[i+1].z + v[i+1].w*v[i+1].w;
    s2 += v[i+2].x*v[i+2].x + v[i+2].y*v[i+2].y + v[i+2].z*v[i+2].z + v[i+2].w*v[i+2].w;
    s3 += v[i+3].x*v[i+3].x + v[i+3].y*v[i+3].y + v[i+3].z*v[i+3].z + v[i+3].w*v[i+3].w;
  }
  float s = (s0 + s1) + (s2 + s3);
  #pragma unroll
  for (int off = 32; off; off >>= 1) s += __shfl_down(s, off);
  __shared__ float wsum[4];
  __shared__ float rshare;
  if ((threadIdx.x & 63) == 0) wsum[threadIdx.x >> 6] = s;
  __syncthreads();
  if (threadIdx.x == 0) {
    float t = wsum[0] + wsum[1] + wsum[2] + wsum[3];
    rshare = 1.f / fmaxf(sqrtf(t), 1e-12f);
  }
  __syncthreads();
  float rinv = rshare;
  unsigned short* dst = (isK ? kbf : qbf) + (size_t)r * NN;
  #pragma unroll
  for (int i = 0; i < 16; ++i) {
    ushort4 o;
    o.x = f2bf(v[i].x * rinv); o.y = f2bf(v[i].y * rinv);
    o.z = f2bf(v[i].z * rinv); o.w = f2bf(v[i].w * rinv);
    *(ushort4*)(dst + ((size_t)threadIdx.x + i*256) * 4) = o;
  }
}

// ---------------- K2: Gram (qn . kn), split-K partials, pure bf16 loads -----
__global__ __launch_bounds__(256) void k_gram(
    const unsigned short* __restrict__ qbf, const unsigned short* __restrict__ kbf,
    float* __restrict__ partial)
{
  int bh = blockIdx.x;     // 32
  int chunk = blockIdx.y;  // 16
  int wave = threadIdx.x >> 6, lane = threadIdx.x & 63;
  int b = bh >> 3, h = bh & 7;
  size_t base = ((size_t)(b*CC + h*HD)) * NN;
  int lrow = lane & 15, lk = (lane >> 4) << 3;
  int kstart = chunk*1024 + wave*256;
  f32x4 acc[3][3] = {};
  for (int ks = 0; ks < 8; ++ks) {
    int kpos = kstart + ks*32 + lk;
    bf16x8 a[3], bb[3];
    #pragma unroll
    for (int t = 0; t < 3; ++t) {
      int rr = t*16 + lrow;
      a[t]  = *(const bf16x8*)(qbf + base + (size_t)rr * NN + kpos);
      bb[t] = *(const bf16x8*)(kbf + base + (size_t)rr * NN + kpos);
    }
    #pragma unroll
    for (int i = 0; i < 3; ++i)
      #pragma unroll
      for (int j = 0; j < 3; ++j)
        acc[i][j] = __builtin_amdgcn_mfma_f32_16x16x32_bf16(a[i], bb[j], acc[i][j], 0, 0, 0);
  }
  // cross-wave reduce in LDS
  __shared__ float red[4][HD][HD+1];
  #pragma unroll
  for (int i = 0; i < 3; ++i)
    #pragma unroll
    for (int j = 0; j < 3; ++j)
      #pragma unroll
      for (int m = 0; m < 4; ++m) {
        int rr = i*16 + (lane>>4)*4 + m;
        int cc2 = j*16 + (lane&15);
        red[wave][rr][cc2] = acc[i][j][m];
      }
  __syncthreads();
  float* pout = partial + ((size_t)bh*16 + chunk) * (HD*HD);
  for (int e = threadIdx.x; e < HD*HD; e += 256) {
    int r = e / HD, c = e % HD;
    pout[e] = red[0][r][c] + red[1][r][c] + red[2][r][c] + red[3][r][c];
  }
}

// ---------------- K3a: reduce 16 partials + temperature + softmax ----------
__global__ __launch_bounds__(256) void k_redsm(
    const float* __restrict__ partial, const float* __restrict__ temp,
    float* __restrict__ attn_out)
{
  int bh = blockIdx.x; int h = bh & 7;
  __shared__ float attn[HD][HD+1];
  const float* p = partial + (size_t)bh * 16 * (HD*HD);
  float tscale = temp[h];
  for (int e = threadIdx.x; e < HD*HD; e += 256) {
    float s = 0.f;
    #pragma unroll
    for (int c2 = 0; c2 < 16; ++c2) s += p[c2*(HD*HD) + e];
    attn[e/HD][e%HD] = s * tscale;
  }
  __syncthreads();
  if (threadIdx.x < HD) {
    float* rowp = attn[threadIdx.x];
    float m = rowp[0];
    for (int j = 1; j < HD; ++j) m = fmaxf(m, rowp[j]);
    float sum = 0.f;
    for (int j = 0; j < HD; ++j) { float e = expf(rowp[j]-m); rowp[j] = e; sum += e; }
    float inv = 1.f / sum;
    for (int j = 0; j < HD; ++j) rowp[j] *= inv;
  }
  __syncthreads();
  float* ao = attn_out + (size_t)bh * (HD*HD);
  for (int e = threadIdx.x; e < HD*HD; e += 256)
    ao[e] = attn[e/HD][e%HD];
}

// ---------------- K3b: M = projW_h @ attn_h (bf16), d4-vectorized ----------
__global__ __launch_bounds__(256) void k_m(
    const float* __restrict__ attn, const float* __restrict__ proj_w,
    unsigned short* __restrict__ Mbf)
{
  int b = blockIdx.x, ot = blockIdx.y;  // grid (4, 24)
  int o0 = ot * 16;
  __shared__ float sw[16*CC];           // 24.6 KB
  __shared__ float sa[HEADS*HD*HD];     // 73.7 KB
  const float* ab = attn + (size_t)b * HEADS * HD * HD;
  for (int i = threadIdx.x; i < HEADS*HD*HD; i += 256) sa[i] = ab[i];
  for (int i = threadIdx.x; i < 16*CC; i += 256)
    sw[i] = proj_w[(size_t)(o0 + i/CC)*CC + (i%CC)];
  __syncthreads();
  // idx over [o in 16][col4 in 96]: 4 consecutive outputs per thread
  for (int idx = threadIdx.x; idx < 16*96; idx += 256) {
    int o = idx / 96, c4 = idx % 96;
    int col = c4 * 4;
    int h = col / HD, d = col % HD;
    const float* wp = sw + o*CC + h*HD;
    const float* ap = sa + h*HD*HD + d;
    f32x4 s = {0.f, 0.f, 0.f, 0.f};
    #pragma unroll
    for (int c2 = 0; c2 < HD; ++c2) {
      float w = wp[c2];
      f32x4 av = *(const f32x4*)(ap + c2*HD);
      s += w * av;
    }
    ushort4 o4;
    o4.x = f2bf(s[0]); o4.y = f2bf(s[1]); o4.z = f2bf(s[2]); o4.w = f2bf(s[3]);
    *(ushort4*)(Mbf + ((size_t)b*CC + o0 + o)*CC + col) = o4;
  }
}

// ---------------- K5: out = M @ kbf + bias  (384x16384x384 per batch) -------
#define BM 128
#define BN 128
#define BK 64

__global__ __launch_bounds__(256) void k_final(
    const unsigned short* __restrict__ kbf, const unsigned short* __restrict__ Mbf,
    const float* __restrict__ bias, float* __restrict__ out)
{
  int b = blockIdx.z;
  int bm = blockIdx.y * BM, bn = blockIdx.x * BN;
  int tid = threadIdx.x, lane = tid & 63, wave = tid >> 6;
  int wrow = wave >> 1, wcol = wave & 1;
  __shared__ unsigned short Bt[BN * BK];   // transposed+swizzled [n][k], 16 KB
  char* btb = (char*)Bt;
  const unsigned short* kb = kbf + (size_t)b * CC * NN;
  const unsigned short* Mb = Mbf + (size_t)b * CC * CC;
  f32x4 acc[4][4] = {};
  int lrow = lane & 15, lkg = lane >> 4;
  for (int k0 = 0; k0 < CC; k0 += BK) {
    #pragma unroll
    for (int s = 0; s < 2; ++s) {
      int slot = tid + s*256;
      int cp = slot >> 4;        // dword column (pair of k/channel rows), 0..31
      int ng = slot & 15;        // group of 8 n-columns
      int n0 = ng * 8;
      int c = k0 + cp*2;
      union { uint4 q; unsigned short u[8]; } r0, r1;
      r0.q = *(const uint4*)(kb + (size_t)c*NN + bn + n0);
      r1.q = *(const uint4*)(kb + (size_t)(c+1)*NN + bn + n0);
      #pragma unroll
      for (int i = 0; i < 8; ++i) {
        int n = n0 + i;
        unsigned int val = (unsigned int)r0.u[i] | ((unsigned int)r1.u[i] << 16);
        int pc = (cp>>2) ^ (n & 7) ^ ((n >> 3) & 7);
        *(unsigned int*)(btb + n*128 + (pc<<4) + ((cp&3)<<2)) = val;
      }
    }
    __syncthreads();
    #pragma unroll
    for (int kk = 0; kk < BK; kk += 32) {
      bf16x8 af[4], bfr[4];
      #pragma unroll
      for (int t = 0; t < 4; ++t) {
        int o = bm + wrow*64 + t*16 + lrow;
        af[t] = *(const bf16x8*)(Mb + (size_t)o*CC + (k0 + kk + (lkg<<3)));
        int n = wcol*64 + t*16 + lrow;
        int lc = (kk>>3) + lkg;
        int pc = lc ^ (n & 7) ^ ((n >> 3) & 7);
        bfr[t] = *(const bf16x8*)(btb + n*128 + (pc<<4));
      }
      #pragma unroll
      for (int i = 0; i < 4; ++i)
        #pragma unroll
        for (int j = 0; j < 4; ++j)
          acc[i][j] = __builtin_amdgcn_mfma_f32_16x16x32_bf16(af[i], bfr[j], acc[i][j], 0, 0, 0);
    }
    __syncthreads();
  }
  #pragma unroll
  for (int i = 0; i < 4; ++i) {
    int obase = bm + wrow*64 + i*16 + lkg*4;
    #pragma unroll
    for (int j = 0; j < 4; ++j) {
      int n = bn + wcol*64 + j*16 + lrow;
      #pragma unroll
      for (int m = 0; m < 4; ++m) {
        int o = obase + m;
        out[((size_t)b*CC + o)*NN + n] = acc[i][j][m] + bias[o];
      }
    }
  }
}

extern "C" void kernel_launch(void* const* d_in, const int* in_sizes, int n_in,
                              void* d_out, int out_size, void* d_ws, size_t ws_size,
                              hipStream_t stream)
{
  const float* in1    = (const float*)d_in[0];
  const float* in2    = (const float*)d_in[1];
  const float* temp   = (const float*)d_in[2];
  const float* proj_w = (const float*)d_in[3];
  const float* proj_b = (const float*)d_in[4];
  float* out = (float*)d_out;
  char* ws = (char*)d_ws;

  size_t off = 0;
  unsigned short* qbf = (unsigned short*)(ws + off); off += (size_t)NROWS*NN*2;   // 50331648
  unsigned short* kbf = (unsigned short*)(ws + off); off += (size_t)NROWS*NN*2;   // 50331648
  float* partial  = (float*)(ws + off); off += (size_t)32*16*HD*HD*4;             // 4718592
  float* attn_out = (float*)(ws + off); off += (size_t)32*HD*HD*4;                // 294912
  unsigned short* Mbf = (unsigned short*)(ws + off);                              // 1179648

  k_norms<<<dim3(2*NROWS), dim3(256), 0, stream>>>(in1, in2, qbf, kbf);
  k_gram<<<dim3(32, 16), dim3(256), 0, stream>>>(qbf, kbf, partial);
  k_redsm<<<dim3(32), dim3(256), 0, stream>>>(partial, temp, attn_out);
  k_m<<<dim3(NB, 24), dim3(256), 0, stream>>>(attn_out, proj_w, Mbf);
  k_final<<<dim3(NN/BN, CC/BM, NB), dim3(256), 0, stream>>>(kbf, Mbf, proj_b, out);
}

// Round 9
// 156.336 us; speedup vs baseline: 1.5061x; 1.0143x over previous
//
#include <hip/hip_runtime.h>
#include <hip/hip_bf16.h>

#define NB 4
#define CC 384
#define HEADS 8
#define HD 48
#define NN 16384          // H*W
#define NROWS (NB*CC)     // 1536

typedef __attribute__((ext_vector_type(8))) short bf16x8;
typedef __attribute__((ext_vector_type(4))) float f32x4;

__device__ __forceinline__ unsigned short f2bf(float f) {
  __hip_bfloat16 h = __float2bfloat16(f);
  return __builtin_bit_cast(unsigned short, h);
}

// ---------------- K1: pure stream: bf16(raw) copy + row sumsq side-chain ----
// Block-per-row, 256 threads x 16 float4 slots = full 16384-elem row.
// Stores depend ONLY on loads (normalization refolded downstream), so the
// streaming loop has no barrier; the rinv reduction is a cheap tail.
__global__ __launch_bounds__(256) void k_conv(
    const float* __restrict__ in1, const float* __restrict__ in2,
    unsigned short* __restrict__ qbf, unsigned short* __restrict__ kbf,
    float* __restrict__ rinv_q, float* __restrict__ rinv_k)
{
  int row = blockIdx.x;            // 0..3071
  bool isK = row >= NROWS;
  int r = isK ? row - NROWS : row;
  const float4* src = (const float4*)((isK ? in2 : in1) + (size_t)r * NN);
  ushort4* dst = (ushort4*)(((isK ? kbf : qbf)) + (size_t)r * NN);
  float s0 = 0.f, s1 = 0.f, s2 = 0.f, s3 = 0.f;
  #pragma unroll
  for (int i = 0; i < 4; ++i) {
    float4 v0 = src[threadIdx.x + (4*i+0)*256];
    float4 v1 = src[threadIdx.x + (4*i+1)*256];
    float4 v2 = src[threadIdx.x + (4*i+2)*256];
    float4 v3 = src[threadIdx.x + (4*i+3)*256];
    ushort4 o0, o1, o2, o3;
    o0.x = f2bf(v0.x); o0.y = f2bf(v0.y); o0.z = f2bf(v0.z); o0.w = f2bf(v0.w);
    o1.x = f2bf(v1.x); o1.y = f2bf(v1.y); o1.z = f2bf(v1.z); o1.w = f2bf(v1.w);
    o2.x = f2bf(v2.x); o2.y = f2bf(v2.y); o2.z = f2bf(v2.z); o2.w = f2bf(v2.w);
    o3.x = f2bf(v3.x); o3.y = f2bf(v3.y); o3.z = f2bf(v3.z); o3.w = f2bf(v3.w);
    dst[threadIdx.x + (4*i+0)*256] = o0;
    dst[threadIdx.x + (4*i+1)*256] = o1;
    dst[threadIdx.x + (4*i+2)*256] = o2;
    dst[threadIdx.x + (4*i+3)*256] = o3;
    s0 += v0.x*v0.x + v0.y*v0.y + v0.z*v0.z + v0.w*v0.w;
    s1 += v1.x*v1.x + v1.y*v1.y + v1.z*v1.z + v1.w*v1.w;
    s2 += v2.x*v2.x + v2.y*v2.y + v2.z*v2.z + v2.w*v2.w;
    s3 += v3.x*v3.x + v3.y*v3.y + v3.z*v3.z + v3.w*v3.w;
  }
  float s = (s0 + s1) + (s2 + s3);
  #pragma unroll
  for (int off = 32; off; off >>= 1) s += __shfl_down(s, off);
  __shared__ float wsum[4];
  if ((threadIdx.x & 63) == 0) wsum[threadIdx.x >> 6] = s;
  __syncthreads();
  if (threadIdx.x == 0) {
    float t = wsum[0] + wsum[1] + wsum[2] + wsum[3];
    (isK ? rinv_k : rinv_q)[r] = 1.f / fmaxf(sqrtf(t), 1e-12f);
  }
}

// ---------------- K2: raw Gram (q0 . k0), split-K partials ------------------
__global__ __launch_bounds__(256) void k_gram(
    const unsigned short* __restrict__ qbf, const unsigned short* __restrict__ kbf,
    float* __restrict__ partial)
{
  int bh = blockIdx.x;     // 32
  int chunk = blockIdx.y;  // 16
  int wave = threadIdx.x >> 6, lane = threadIdx.x & 63;
  int b = bh >> 3, h = bh & 7;
  size_t base = ((size_t)(b*CC + h*HD)) * NN;
  int lrow = lane & 15, lk = (lane >> 4) << 3;
  int kstart = chunk*1024 + wave*256;
  f32x4 acc[3][3] = {};
  for (int ks = 0; ks < 8; ++ks) {
    int kpos = kstart + ks*32 + lk;
    bf16x8 a[3], bb[3];
    #pragma unroll
    for (int t = 0; t < 3; ++t) {
      int rr = t*16 + lrow;
      a[t]  = *(const bf16x8*)(qbf + base + (size_t)rr * NN + kpos);
      bb[t] = *(const bf16x8*)(kbf + base + (size_t)rr * NN + kpos);
    }
    #pragma unroll
    for (int i = 0; i < 3; ++i)
      #pragma unroll
      for (int j = 0; j < 3; ++j)
        acc[i][j] = __builtin_amdgcn_mfma_f32_16x16x32_bf16(a[i], bb[j], acc[i][j], 0, 0, 0);
  }
  __shared__ float red[4][HD][HD+1];
  #pragma unroll
  for (int i = 0; i < 3; ++i)
    #pragma unroll
    for (int j = 0; j < 3; ++j)
      #pragma unroll
      for (int m = 0; m < 4; ++m) {
        int rr = i*16 + (lane>>4)*4 + m;
        int cc2 = j*16 + (lane&15);
        red[wave][rr][cc2] = acc[i][j][m];
      }
  __syncthreads();
  float* pout = partial + ((size_t)bh*16 + chunk) * (HD*HD);
  for (int e = threadIdx.x; e < HD*HD; e += 256) {
    int r = e / HD, c = e % HD;
    pout[e] = red[0][r][c] + red[1][r][c] + red[2][r][c] + red[3][r][c];
  }
}

// ---------------- K3a: reduce + rinv scaling + temperature + softmax --------
__global__ __launch_bounds__(256) void k_redsm(
    const float* __restrict__ partial, const float* __restrict__ temp,
    const float* __restrict__ rinv_q, const float* __restrict__ rinv_k,
    float* __restrict__ attn_out)
{
  int bh = blockIdx.x; int b = bh >> 3, h = bh & 7;
  __shared__ float attn[HD][HD+1];
  __shared__ float rqs[HD], rks[HD];
  if (threadIdx.x < HD) {
    rqs[threadIdx.x] = rinv_q[b*CC + h*HD + threadIdx.x];
    rks[threadIdx.x] = rinv_k[b*CC + h*HD + threadIdx.x];
  }
  const float* p = partial + (size_t)bh * 16 * (HD*HD);
  float tscale = temp[h];
  __syncthreads();
  for (int e = threadIdx.x; e < HD*HD; e += 256) {
    float s = 0.f;
    #pragma unroll
    for (int c2 = 0; c2 < 16; ++c2) s += p[c2*(HD*HD) + e];
    attn[e/HD][e%HD] = s * tscale * rqs[e/HD] * rks[e%HD];
  }
  __syncthreads();
  if (threadIdx.x < HD) {
    float* rowp = attn[threadIdx.x];
    float m = rowp[0];
    for (int j = 1; j < HD; ++j) m = fmaxf(m, rowp[j]);
    float sum = 0.f;
    for (int j = 0; j < HD; ++j) { float e = expf(rowp[j]-m); rowp[j] = e; sum += e; }
    float inv = 1.f / sum;
    for (int j = 0; j < HD; ++j) rowp[j] *= inv;
  }
  __syncthreads();
  float* ao = attn_out + (size_t)bh * (HD*HD);
  for (int e = threadIdx.x; e < HD*HD; e += 256)
    ao[e] = attn[e/HD][e%HD];
}

// ---------------- K3b: M = (projW_h @ attn_h) * rinv_k[col], bf16 ----------
__global__ __launch_bounds__(256) void k_m(
    const float* __restrict__ attn, const float* __restrict__ proj_w,
    const float* __restrict__ rinv_k, unsigned short* __restrict__ Mbf)
{
  int b = blockIdx.x, ot = blockIdx.y;  // grid (4, 24)
  int o0 = ot * 16;
  __shared__ float sw[16*CC];           // 24.6 KB
  __shared__ float sa[HEADS*HD*HD];     // 73.7 KB
  const float* ab = attn + (size_t)b * HEADS * HD * HD;
  for (int i = threadIdx.x; i < HEADS*HD*HD; i += 256) sa[i] = ab[i];
  for (int i = threadIdx.x; i < 16*CC; i += 256)
    sw[i] = proj_w[(size_t)(o0 + i/CC)*CC + (i%CC)];
  __syncthreads();
  for (int idx = threadIdx.x; idx < 16*96; idx += 256) {
    int o = idx / 96, c4 = idx % 96;
    int col = c4 * 4;
    int h = col / HD, d = col % HD;
    const float* wp = sw + o*CC + h*HD;
    const float* ap = sa + h*HD*HD + d;
    f32x4 s = {0.f, 0.f, 0.f, 0.f};
    #pragma unroll
    for (int c2 = 0; c2 < HD; ++c2) {
      float w = wp[c2];
      f32x4 av = *(const f32x4*)(ap + c2*HD);
      s += w * av;
    }
    f32x4 rk = *(const f32x4*)(rinv_k + b*CC + col);
    s *= rk;
    ushort4 o4;
    o4.x = f2bf(s[0]); o4.y = f2bf(s[1]); o4.z = f2bf(s[2]); o4.w = f2bf(s[3]);
    *(ushort4*)(Mbf + ((size_t)b*CC + o0 + o)*CC + col) = o4;
  }
}

// ---------------- K5: out = M @ k0 + bias  (384x16384x384 per batch) --------
#define BM 128
#define BN 128
#define BK 64

__global__ __launch_bounds__(256) void k_final(
    const unsigned short* __restrict__ kbf, const unsigned short* __restrict__ Mbf,
    const float* __restrict__ bias, float* __restrict__ out)
{
  int b = blockIdx.z;
  int bm = blockIdx.y * BM, bn = blockIdx.x * BN;
  int tid = threadIdx.x, lane = tid & 63, wave = tid >> 6;
  int wrow = wave >> 1, wcol = wave & 1;
  __shared__ unsigned short Bt[BN * BK];   // transposed+swizzled [n][k], 16 KB
  char* btb = (char*)Bt;
  const unsigned short* kb = kbf + (size_t)b * CC * NN;
  const unsigned short* Mb = Mbf + (size_t)b * CC * CC;
  f32x4 acc[4][4] = {};
  int lrow = lane & 15, lkg = lane >> 4;
  for (int k0 = 0; k0 < CC; k0 += BK) {
    #pragma unroll
    for (int s = 0; s < 2; ++s) {
      int slot = tid + s*256;
      int cp = slot >> 4;        // dword column (pair of k/channel rows), 0..31
      int ng = slot & 15;        // group of 8 n-columns
      int n0 = ng * 8;
      int c = k0 + cp*2;
      union { uint4 q; unsigned short u[8]; } r0, r1;
      r0.q = *(const uint4*)(kb + (size_t)c*NN + bn + n0);
      r1.q = *(const uint4*)(kb + (size_t)(c+1)*NN + bn + n0);
      #pragma unroll
      for (int i = 0; i < 8; ++i) {
        int n = n0 + i;
        unsigned int val = (unsigned int)r0.u[i] | ((unsigned int)r1.u[i] << 16);
        int pc = (cp>>2) ^ (n & 7) ^ ((n >> 3) & 7);
        *(unsigned int*)(btb + n*128 + (pc<<4) + ((cp&3)<<2)) = val;
      }
    }
    __syncthreads();
    #pragma unroll
    for (int kk = 0; kk < BK; kk += 32) {
      bf16x8 af[4], bfr[4];
      #pragma unroll
      for (int t = 0; t < 4; ++t) {
        int o = bm + wrow*64 + t*16 + lrow;
        af[t] = *(const bf16x8*)(Mb + (size_t)o*CC + (k0 + kk + (lkg<<3)));
        int n = wcol*64 + t*16 + lrow;
        int lc = (kk>>3) + lkg;
        int pc = lc ^ (n & 7) ^ ((n >> 3) & 7);
        bfr[t] = *(const bf16x8*)(btb + n*128 + (pc<<4));
      }
      #pragma unroll
      for (int i = 0; i < 4; ++i)
        #pragma unroll
        for (int j = 0; j < 4; ++j)
          acc[i][j] = __builtin_amdgcn_mfma_f32_16x16x32_bf16(af[i], bfr[j], acc[i][j], 0, 0, 0);
    }
    __syncthreads();
  }
  #pragma unroll
  for (int i = 0; i < 4; ++i) {
    int obase = bm + wrow*64 + i*16 + lkg*4;
    #pragma unroll
    for (int j = 0; j < 4; ++j) {
      int n = bn + wcol*64 + j*16 + lrow;
      #pragma unroll
      for (int m = 0; m < 4; ++m) {
        int o = obase + m;
        out[((size_t)b*CC + o)*NN + n] = acc[i][j][m] + bias[o];
      }
    }
  }
}

extern "C" void kernel_launch(void* const* d_in, const int* in_sizes, int n_in,
                              void* d_out, int out_size, void* d_ws, size_t ws_size,
                              hipStream_t stream)
{
  const float* in1    = (const float*)d_in[0];
  const float* in2    = (const float*)d_in[1];
  const float* temp   = (const float*)d_in[2];
  const float* proj_w = (const float*)d_in[3];
  const float* proj_b = (const float*)d_in[4];
  float* out = (float*)d_out;
  char* ws = (char*)d_ws;

  size_t off = 0;
  unsigned short* qbf = (unsigned short*)(ws + off); off += (size_t)NROWS*NN*2;   // 50331648
  unsigned short* kbf = (unsigned short*)(ws + off); off += (size_t)NROWS*NN*2;   // 50331648
  float* partial  = (float*)(ws + off); off += (size_t)32*16*HD*HD*4;             // 4718592
  float* attn_out = (float*)(ws + off); off += (size_t)32*HD*HD*4;                // 294912
  float* rinv_q   = (float*)(ws + off); off += NROWS*4;                           // 6144
  float* rinv_k   = (float*)(ws + off); off += NROWS*4;                           // 6144
  unsigned short* Mbf = (unsigned short*)(ws + off);                              // 1179648

  k_conv<<<dim3(2*NROWS), dim3(256), 0, stream>>>(in1, in2, qbf, kbf, rinv_q, rinv_k);
  k_gram<<<dim3(32, 16), dim3(256), 0, stream>>>(qbf, kbf, partial);
  k_redsm<<<dim3(32), dim3(256), 0, stream>>>(partial, temp, rinv_q, rinv_k, attn_out);
  k_m<<<dim3(NB, 24), dim3(256), 0, stream>>>(attn_out, proj_w, rinv_k, Mbf);
  k_final<<<dim3(NN/BN, CC/BM, NB), dim3(256), 0, stream>>>(kbf, Mbf, proj_b, out);
}